// Round 15
// baseline (262.988 us; speedup 1.0000x reference)
//
#include <hip/hip_runtime.h>

#define BATCH 65536
#define HID   512
#define NCLS  1000
#define NCLSP 1024

typedef long i64;   // 8 packed fp8 (2 VGPRs) for MFMA A/B operands
typedef float f32x4 __attribute__((ext_vector_type(4)));
typedef float f32x2 __attribute__((ext_vector_type(2)));
typedef unsigned short u16;
typedef unsigned int u32;
typedef unsigned char u8;

// pack 4 floats -> 4 fp8 e4m3 bytes (k-order a,b,c,d)
__device__ __forceinline__ u32 pk4(float a, float b, float c, float d) {
  u32 r = 0;
  r = (u32)__builtin_amdgcn_cvt_pk_fp8_f32(a, b, (int)r, false);
  r = (u32)__builtin_amdgcn_cvt_pk_fp8_f32(c, d, (int)r, true);
  return r;
}
__device__ __forceinline__ u8 pk1(float a) {
  return (u8)(__builtin_amdgcn_cvt_pk_fp8_f32(a, 0.f, 0, false) & 0xff);
}

// ---------------- ws layout ----------------
// counts  int[1024]        @ 0
// accum   double[8]        @ 4096   (0 stab, 1 center, 2 sep, 3 brier)
// sq      float[1024]      @ 8192
// offsets int[1024]        @ 12288  (after k_scatter: segment END)
// order   int[65536]       @ 16384
// centers float[1024*512]  @ 278528
// wb8     u8[16*1024*32]   @ 2375680  (frag-linear fp8 of 16*W; 512 KB)
#define WS_END 2899968

// ---------------- zero counts + accum ----------------
__global__ void k_zero(int* __restrict__ counts, double* __restrict__ accum) {
  const int t = threadIdx.x;
  counts[t] = 0;
  if (t < 8) accum[t] = 0.0;
}

// ---------------- fused: label histogram (blocks 0-255) + W->fp8 conv (blocks 256-767) ----------------
__global__ void k_hw(const int* __restrict__ labels, int* __restrict__ counts,
                     const float* __restrict__ W, u32* __restrict__ wb) {
  const int b = blockIdx.x;
  if (b < 256) {
    const int i = b * 256 + threadIdx.x;
    if (i < BATCH) atomicAdd(counts + labels[i], 1);
  } else {
    const int j = (b - 256) * 256 + threadIdx.x;   // 131072 total
    const int kc = j >> 13, col = (j >> 3) & 1023, kg = (j >> 1) & 3, i0 = (j & 1) * 4;
    const int k = kc * 32 + kg * 8 + i0;
    float w0 = 0.f, w1 = 0.f, w2 = 0.f, w3 = 0.f;
    if (col < NCLS) {
      w0 = W[(size_t)(k + 0) * NCLS + col] * 16.f;
      w1 = W[(size_t)(k + 1) * NCLS + col] * 16.f;
      w2 = W[(size_t)(k + 2) * NCLS + col] * 16.f;
      w3 = W[(size_t)(k + 3) * NCLS + col] * 16.f;
    }
    wb[j] = pk4(w0, w1, w2, w3);
  }
}

// ---------------- exclusive prefix sum over 1024 bins (1 block) ----------------
__global__ void k_scan(const int* __restrict__ counts, int* __restrict__ offsets) {
  __shared__ int tmp[1024];
  const int t = threadIdx.x;
  const int v = counts[t];
  tmp[t] = v;
  __syncthreads();
  for (int d = 1; d < 1024; d <<= 1) {
    int u = (t >= d) ? tmp[t - d] : 0;
    __syncthreads();
    tmp[t] += u;
    __syncthreads();
  }
  offsets[t] = tmp[t] - v;   // exclusive
}

// ---------------- scatter row indices into class-sorted order ----------------
__global__ void k_scatter(const int* __restrict__ labels, int* __restrict__ offsets,
                          int* __restrict__ order) {
  const int i = blockIdx.x * blockDim.x + threadIdx.x;
  if (i < BATCH) {
    const int pos = atomicAdd(offsets + labels[i], 1);
    order[pos] = i;
  }
}

// ---------------- segmented mean/center-loss, float4-vectorized gather ----------------
// 1024 blocks (1 class each) x 512 threads: 4 row-groups x 128 col-quads.
// center loss per (class,col): sum(x-c)^2 = sum(x^2) - cnt*c^2
__global__ __launch_bounds__(512)
void k_segsum(const float* __restrict__ cls, const int* __restrict__ order,
              const int* __restrict__ offsets, const int* __restrict__ counts,
              const float* __restrict__ cen_in, float* __restrict__ cen,
              float* __restrict__ sq, double* __restrict__ accum) {
  __shared__ float4 sm[512];
  __shared__ float4 qm[512];
  __shared__ float red[16];
  const int c = blockIdx.x;
  const int t = threadIdx.x;
  const int cidx = t & 127;      // cols cidx*4 .. +3
  const int rgrp = t >> 7;       // 0..3
  const int cnt = counts[c];
  const int end = offsets[c];
  const int start = end - cnt;
  float4 s = make_float4(0.f, 0.f, 0.f, 0.f);
  float4 q = make_float4(0.f, 0.f, 0.f, 0.f);
  for (int i = start + rgrp; i < end; i += 4) {
    const float4 x = *(const float4*)(cls + (size_t)order[i] * HID + cidx * 4);
    s.x += x.x; s.y += x.y; s.z += x.z; s.w += x.w;
    q.x = fmaf(x.x, x.x, q.x); q.y = fmaf(x.y, x.y, q.y);
    q.z = fmaf(x.z, x.z, q.z); q.w = fmaf(x.w, x.w, q.w);
  }
  sm[t] = s; qm[t] = q;
  __syncthreads();
  float p = 0.f, cp = 0.f;
  if (t < 128) {
    float4 S = sm[t], Q = qm[t];
    float4 a = sm[128 + t], b = sm[256 + t], d = sm[384 + t];
    S.x += a.x + b.x + d.x; S.y += a.y + b.y + d.y;
    S.z += a.z + b.z + d.z; S.w += a.w + b.w + d.w;
    a = qm[128 + t]; b = qm[256 + t]; d = qm[384 + t];
    Q.x += a.x + b.x + d.x; Q.y += a.y + b.y + d.y;
    Q.z += a.z + b.z + d.z; Q.w += a.w + b.w + d.w;
    float4 v;
    if (cnt > 0) {
      const float fc = (float)cnt, inv = 1.f / fc;
      v = make_float4(S.x * inv, S.y * inv, S.z * inv, S.w * inv);
      cp = (Q.x - fc * v.x * v.x) + (Q.y - fc * v.y * v.y)
         + (Q.z - fc * v.z * v.z) + (Q.w - fc * v.w * v.w);
    } else {
      v = (c < NCLS) ? *(const float4*)(cen_in + (size_t)c * HID + t * 4)
                     : make_float4(0.f, 0.f, 0.f, 0.f);
      cp = 0.f;
    }
    *(float4*)(cen + (size_t)c * HID + t * 4) = v;
    p = v.x * v.x + v.y * v.y + v.z * v.z + v.w * v.w;
  }
  #pragma unroll
  for (int sh = 32; sh; sh >>= 1) { p += __shfl_xor(p, sh); cp += __shfl_xor(cp, sh); }
  if (t < 128 && (t & 63) == 0) { red[t >> 6] = p; red[8 + (t >> 6)] = cp; }
  __syncthreads();
  if (t == 0) {
    sq[c] = red[0] + red[1];
    atomicAdd(accum + 1, (double)(red[8] + red[9]));
  }
}

// ---------------- separation: Gram + exp-sum (64x64 tiles, 8 waves/block) ----------------
// 256 blocks x 512 threads; thread = (tx 0..15, ty 0..31), acc[2][4]: rows {ty, ty+32}, cols tx*4..+3.
__global__ __launch_bounds__(512)
void k_sep(const float* __restrict__ cen, const float* __restrict__ sq,
           double* __restrict__ accum) {
  __shared__ float As[16][64];
  __shared__ float Bs[16][64];
  __shared__ float red[8];
  const int bi = blockIdx.x >> 4, bj = blockIdx.x & 15;
  const int tx = threadIdx.x & 15, ty = threadIdx.x >> 4;   // ty 0..31
  const int lrow = threadIdx.x & 63, lkq = threadIdx.x >> 6; // 0..7
  float acc[2][4] = {};
  for (int k0 = 0; k0 < HID; k0 += 16) {
    __syncthreads();
    f32x2 a = *(const f32x2*)(cen + (size_t)(bi * 64 + lrow) * HID + k0 + lkq * 2);
    f32x2 b = *(const f32x2*)(cen + (size_t)(bj * 64 + lrow) * HID + k0 + lkq * 2);
    As[lkq * 2 + 0][lrow] = a[0]; As[lkq * 2 + 1][lrow] = a[1];
    Bs[lkq * 2 + 0][lrow] = b[0]; Bs[lkq * 2 + 1][lrow] = b[1];
    __syncthreads();
    #pragma unroll
    for (int k = 0; k < 16; ++k) {
      const float a0 = As[k][ty];
      const float a1 = As[k][ty + 32];
      const float4 bv = *(const float4*)&Bs[k][tx * 4];
      acc[0][0] = fmaf(a0, bv.x, acc[0][0]); acc[0][1] = fmaf(a0, bv.y, acc[0][1]);
      acc[0][2] = fmaf(a0, bv.z, acc[0][2]); acc[0][3] = fmaf(a0, bv.w, acc[0][3]);
      acc[1][0] = fmaf(a1, bv.x, acc[1][0]); acc[1][1] = fmaf(a1, bv.y, acc[1][1]);
      acc[1][2] = fmaf(a1, bv.z, acc[1][2]); acc[1][3] = fmaf(a1, bv.w, acc[1][3]);
    }
  }
  float part = 0.f;
  #pragma unroll
  for (int r = 0; r < 2; ++r) {
    const int i = bi * 64 + ty + r * 32;
    #pragma unroll
    for (int s2 = 0; s2 < 4; ++s2) {
      const int j = bj * 64 + tx * 4 + s2;
      if (i < NCLS && j < NCLS) {
        float d2 = fmaxf(sq[i] + sq[j] - 2.f * acc[r][s2], 0.f);
        float dist = sqrtf(d2);
        part += __expf((i == j ? 1.f : 0.f) - dist);
      }
    }
  }
  #pragma unroll
  for (int sh = 32; sh; sh >>= 1) part += __shfl_xor(part, sh);
  if ((threadIdx.x & 63) == 0) red[threadIdx.x >> 6] = part;
  __syncthreads();
  if (threadIdx.x == 0) {
    float acc8 = 0.f;
    #pragma unroll
    for (int i = 0; i < 8; ++i) acc8 += red[i];
    atomicAdd(accum + 2, (double)acc8);
  }
}

// ---------------- fused stab: in-kernel fp8 staging + MFMA (B-prefetch) + epilogue ----------------
// (round-12 kernel, unchanged — 166 us, VGPR 32, occ 84%)
__global__ __launch_bounds__(1024, 8)
void k_gemm(const float* __restrict__ cls, const float* __restrict__ noise,
            const float* __restrict__ logits, const int* __restrict__ labels,
            const float* __restrict__ bias, const u8* __restrict__ wb,
            double* __restrict__ accum) {
  __shared__ u8 Apan[32 * 512];      // 16 KB fp8 A-panel (swizzled)
  __shared__ u8 lntile[32 * 1024];   // 32 KB fp8 ln tile
  __shared__ float redf[32];
  const int lane = threadIdx.x & 63;
  const int w = threadIdx.x >> 6;    // 0..15
  const int row0 = blockIdx.x * 32;
  const int l15 = lane & 15, lkg = lane >> 4;

  // ---- phase 0: stage 32x512 fp8 A-panel (16 elems/thread, XOR-swizzled dest) ----
  {
    const int row_loc = threadIdx.x >> 5;            // 0..31
    const int k0 = (threadIdx.x & 31) * 16;          // 16 elems per thread
    const int sw = ((row_loc & 7) << 3) | (((row_loc >> 3) & 1) << 6);
    const float* cp = cls   + (size_t)(row0 + row_loc) * HID;
    const float* np = noise + (size_t)(row0 + row_loc) * HID;
    #pragma unroll
    for (int q = 0; q < 2; ++q) {
      const int g = k0 + q * 8;
      const int k = g ^ sw;
      float4 a0 = *(const float4*)(cp + k), a1 = *(const float4*)(cp + k + 4);
      float4 n0 = *(const float4*)(np + k), n1 = *(const float4*)(np + k + 4);
      uint2 p;
      p.x = pk4(fmaf(0.1f, n0.x, a0.x), fmaf(0.1f, n0.y, a0.y),
                fmaf(0.1f, n0.z, a0.z), fmaf(0.1f, n0.w, a0.w));
      p.y = pk4(fmaf(0.1f, n1.x, a1.x), fmaf(0.1f, n1.y, a1.y),
                fmaf(0.1f, n1.z, a1.z), fmaf(0.1f, n1.w, a1.w));
      *(uint2*)&Apan[row_loc * 512 + g] = p;
    }
  }
  __syncthreads();

  // ---- phase 2: 16 K-steps with one-deep register B-prefetch ----
  f32x4 acc[2][4] = {};
  const int swr = ((l15 & 7) << 3) | ((l15 >> 3) << 6);
  const u8* bb0 = wb + (w * 64 + l15) * 32 + lkg * 8;
  i64 bcur[4];
  #pragma unroll
  for (int ct = 0; ct < 4; ++ct) bcur[ct] = *(const i64*)(bb0 + ct * 512);
  for (int kc = 0; kc < 16; ++kc) {
    const int kn = (kc < 15) ? kc + 1 : 15;          // clamped prefetch index (uniform)
    const u8* bbn = bb0 + (size_t)kn * 32768;
    i64 bnxt[4];
    #pragma unroll
    for (int ct = 0; ct < 4; ++ct) bnxt[ct] = *(const i64*)(bbn + ct * 512);
    i64 af0 = *(const i64*)&Apan[(l15)      * 512 + ((kc * 32 + lkg * 8) ^ swr)];
    i64 af1 = *(const i64*)&Apan[(16 + l15) * 512 + ((kc * 32 + lkg * 8) ^ swr)];
    #pragma unroll
    for (int ct = 0; ct < 4; ++ct) {
      acc[0][ct] = __builtin_amdgcn_mfma_f32_16x16x32_fp8_fp8(af0, bcur[ct], acc[0][ct], 0, 0, 0);
      acc[1][ct] = __builtin_amdgcn_mfma_f32_16x16x32_fp8_fp8(af1, bcur[ct], acc[1][ct], 0, 0, 0);
    }
    #pragma unroll
    for (int ct = 0; ct < 4; ++ct) bcur[ct] = bnxt[ct];
  }

  // ---- phase 3a: ln = acc/16 + bias -> fp8 into lntile ----
  #pragma unroll
  for (int ct = 0; ct < 4; ++ct) {
    const int col = w * 64 + ct * 16 + l15;
    if (col < NCLS) {
      const float bc = bias[col];
      #pragma unroll
      for (int rt = 0; rt < 2; ++rt) {
        #pragma unroll
        for (int r = 0; r < 4; ++r) {
          const int rowloc = rt * 16 + lkg * 4 + r;
          lntile[rowloc * 1024 + (col ^ ((rowloc & 12) << 2))] =
              pk1(fmaf(acc[rt][ct][r], 0.0625f, bc));
        }
      }
    }
  }
  __syncthreads();

  // ---- phase 3b: single coalesced pass over logits: diff^2 + brier (no max-sub) ----
  float spart = 0.f, bpart = 0.f;
  #pragma unroll
  for (int j = 0; j < 2; ++j) {
    const int rowloc = w * 2 + j;
    const int row = row0 + rowloc;
    const int swz = (rowloc & 12) << 2;
    const u8* lnrow = lntile + rowloc * 1024;
    const float4* lr = (const float4*)(logits + (size_t)row * NCLS);
    const int lab2 = labels[row];
    const float el = __expf(logits[(size_t)row * NCLS + lab2]);
    float S = 0.f, S2 = 0.f;
    #pragma unroll
    for (int it = 0; it < 4; ++it) {
      const int f = it * 64 + lane;
      if (f < 250) {
        float4 lg = lr[f];
        u32 v = *(const u32*)(lnrow + ((f * 4) ^ swz));
        f32x2 lo = __builtin_amdgcn_cvt_pk_f32_fp8((int)v, false);
        f32x2 hi = __builtin_amdgcn_cvt_pk_f32_fp8((int)v, true);
        float d0 = lo[0] - lg.x, d1 = lo[1] - lg.y, d2 = hi[0] - lg.z, d3 = hi[1] - lg.w;
        spart += d0 * d0 + d1 * d1 + d2 * d2 + d3 * d3;
        float e0 = __expf(lg.x), e1 = __expf(lg.y), e2 = __expf(lg.z), e3 = __expf(lg.w);
        S += e0 + e1 + e2 + e3;
        S2 += e0 * e0 + e1 * e1 + e2 * e2 + e3 * e3;
      }
    }
    #pragma unroll
    for (int s = 32; s; s >>= 1) { S += __shfl_xor(S, s); S2 += __shfl_xor(S2, s); }
    bpart += S2 / (S * S) - 2.f * el / S + 1.f;
  }
  #pragma unroll
  for (int s = 32; s; s >>= 1) { spart += __shfl_xor(spart, s); bpart += __shfl_xor(bpart, s); }

  if (lane == 0) { redf[w] = spart; redf[16 + w] = bpart; }
  __syncthreads();
  if (threadIdx.x == 0) {
    float st = 0.f, br = 0.f;
    #pragma unroll
    for (int i = 0; i < 16; ++i) { st += redf[i]; br += redf[16 + i]; }
    atomicAdd(accum + 0, (double)st);
    atomicAdd(accum + 3, (double)br);
  }
}

// ---------------- combine ----------------
__global__ void k_final(const double* __restrict__ accum, float* __restrict__ out) {
  if (threadIdx.x == 0) {
    double stab   = accum[0] / ((double)BATCH * (double)NCLS);
    double center = accum[1] / ((double)BATCH * (double)HID);
    double sep    = accum[2] - (double)NCLS;
    double brier  = accum[3] / (double)BATCH;
    double total  = 1.0 * stab + 0.1 * center + 0.01 * sep + 1.0 * brier;
    out[0] = (float)total;
    out[1] = (float)stab;
    out[2] = (float)center;
    out[3] = (float)sep;
    out[4] = (float)brier;
  }
}

extern "C" void kernel_launch(void* const* d_in, const int* in_sizes, int n_in,
                              void* d_out, int out_size, void* d_ws, size_t ws_size,
                              hipStream_t stream) {
  const float* cls    = (const float*)d_in[0];
  const float* logits = (const float*)d_in[1];
  const int*   labels = (const int*)d_in[2];
  const float* W      = (const float*)d_in[3];
  const float* bias   = (const float*)d_in[4];
  const float* noise  = (const float*)d_in[5];
  const float* cen_in = (const float*)d_in[6];
  float* out = (float*)d_out;
  char* ws = (char*)d_ws;
  if (ws_size < (size_t)WS_END) return;  // fail visibly (out stays poisoned)

  int*    counts  = (int*)(ws + 0);
  double* accum   = (double*)(ws + 4096);
  float*  sq      = (float*)(ws + 8192);
  int*    offsets = (int*)(ws + 12288);
  int*    order   = (int*)(ws + 16384);
  float*  cen     = (float*)(ws + 278528);
  u8*     wb8     = (u8*)(ws + 2375680);

  hipLaunchKernelGGL(k_zero,    dim3(1),    dim3(1024), 0, stream, counts, accum);
  hipLaunchKernelGGL(k_hw,      dim3(768),  dim3(256),  0, stream, labels, counts, W, (u32*)wb8);
  hipLaunchKernelGGL(k_scan,    dim3(1),    dim3(1024), 0, stream, counts, offsets);
  hipLaunchKernelGGL(k_scatter, dim3(256),  dim3(256),  0, stream, labels, offsets, order);
  hipLaunchKernelGGL(k_segsum,  dim3(1024), dim3(512),  0, stream, cls, order, offsets, counts, cen_in, cen, sq, accum);
  hipLaunchKernelGGL(k_sep,     dim3(256),  dim3(512),  0, stream, cen, sq, accum);
  hipLaunchKernelGGL(k_gemm,    dim3(2048), dim3(1024), 0, stream, cls, noise, logits, labels, bias, wb8, accum);
  hipLaunchKernelGGL(k_final,   dim3(1),    dim3(64),   0, stream, accum, out);
}

// Round 16
// 254.493 us; speedup vs baseline: 1.0334x; 1.0334x over previous
//
#include <hip/hip_runtime.h>

#define BATCH 65536
#define HID   512
#define NCLS  1000
#define NCLSP 1024

typedef long i64;   // 8 packed fp8 (2 VGPRs) for MFMA A/B operands
typedef float f32x4 __attribute__((ext_vector_type(4)));
typedef float f32x2 __attribute__((ext_vector_type(2)));
typedef unsigned short u16;
typedef unsigned int u32;
typedef unsigned char u8;

// pack 4 floats -> 4 fp8 e4m3 bytes (k-order a,b,c,d)
__device__ __forceinline__ u32 pk4(float a, float b, float c, float d) {
  u32 r = 0;
  r = (u32)__builtin_amdgcn_cvt_pk_fp8_f32(a, b, (int)r, false);
  r = (u32)__builtin_amdgcn_cvt_pk_fp8_f32(c, d, (int)r, true);
  return r;
}
__device__ __forceinline__ u8 pk1(float a) {
  return (u8)(__builtin_amdgcn_cvt_pk_fp8_f32(a, 0.f, 0, false) & 0xff);
}

// ---------------- ws layout ----------------
// counts  int[1024]        @ 0
// cursor  int[1024]        @ 4096   (scatter cursors, zeroed)
// accum   double[8]        @ 8192   (0 stab, 1 center, 2 sep, 3 brier)
// sq      float[1024]      @ 12288
// offsets int[1024]        @ 16384  (segment END per class)
// order   int[65536]       @ 20480
// centers float[1024*512]  @ 282624
// wb8     u8[16*1024*32]   @ 2383872  (frag-linear fp8 of 16*W; 512 KB)
#define WS_END 2908160

// ---------------- zero counts + cursor + accum ----------------
__global__ void k_zero(int* __restrict__ counts, int* __restrict__ cursor,
                       double* __restrict__ accum) {
  const int t = threadIdx.x;
  counts[t] = 0;
  cursor[t] = 0;
  if (t < 8) accum[t] = 0.0;
}

// ---------------- label histogram ----------------
__global__ void k_hist(const int* __restrict__ labels, int* __restrict__ counts) {
  const int i = blockIdx.x * blockDim.x + threadIdx.x;
  if (i < BATCH) atomicAdd(counts + labels[i], 1);
}

// ---------------- W f32 -> fragment-linear fp8 (scaled x16) ----------------
__global__ void k_wconv(const float* __restrict__ W, u32* __restrict__ wb) {
  const int j = blockIdx.x * blockDim.x + threadIdx.x;   // 131072 total
  const int kc = j >> 13, col = (j >> 3) & 1023, kg = (j >> 1) & 3, i0 = (j & 1) * 4;
  const int k = kc * 32 + kg * 8 + i0;
  float w0 = 0.f, w1 = 0.f, w2 = 0.f, w3 = 0.f;
  if (col < NCLS) {
    w0 = W[(size_t)(k + 0) * NCLS + col] * 16.f;
    w1 = W[(size_t)(k + 1) * NCLS + col] * 16.f;
    w2 = W[(size_t)(k + 2) * NCLS + col] * 16.f;
    w3 = W[(size_t)(k + 3) * NCLS + col] * 16.f;
  }
  wb[j] = pk4(w0, w1, w2, w3);
}

// ---------------- fused scan + scatter ----------------
// 64 blocks x 1024 threads. Each block redundantly computes the exclusive scan of
// counts[1024] (wave shfl_up, 2 barriers — replaces the serial 20-barrier k_scan),
// then scatters its 1024-row slice: pos = scan[lab] + atomicAdd(cursor+lab, 1).
// Block 0 also writes offsets[c] = inclusive scan (segment END, read by k_segsum).
__global__ void k_scatter(const int* __restrict__ labels, const int* __restrict__ counts,
                          int* __restrict__ cursor, int* __restrict__ offsets,
                          int* __restrict__ order) {
  __shared__ int scan[1024];
  __shared__ int wsum[16];
  const int t = threadIdx.x;
  const int v = counts[t];
  int x = v;
  #pragma unroll
  for (int d = 1; d < 64; d <<= 1) {
    int y = __shfl_up(x, d);
    if ((t & 63) >= d) x += y;
  }
  if ((t & 63) == 63) wsum[t >> 6] = x;
  __syncthreads();
  if (t < 16) {
    int s = wsum[t];
    #pragma unroll
    for (int d = 1; d < 16; d <<= 1) {
      int y = __shfl_up(s, d);
      if (t >= d) s += y;
    }
    wsum[t] = s;   // inclusive wave sums
  }
  __syncthreads();
  const int base = (t >= 64) ? wsum[(t >> 6) - 1] : 0;
  const int incl = base + x;
  scan[t] = incl - v;            // exclusive
  if (blockIdx.x == 0) offsets[t] = incl;   // segment END
  __syncthreads();
  const int i = blockIdx.x * 1024 + t;
  if (i < BATCH) {
    const int lab = labels[i];
    const int pos = scan[lab] + atomicAdd(cursor + lab, 1);
    order[pos] = i;
  }
}

// ---------------- segmented mean -> centers, |center|^2, center-loss (round-12 version) ----------------
// center loss per (class, col): sum(x - c)^2 = sum(x^2) - cnt * c^2
__global__ void k_segsum(const float* __restrict__ cls, const int* __restrict__ order,
                         const int* __restrict__ offsets, const int* __restrict__ counts,
                         const float* __restrict__ cen_in, float* __restrict__ cen,
                         float* __restrict__ sq, double* __restrict__ accum) {
  __shared__ float red[8];
  __shared__ float redc[8];
  const int c = blockIdx.x;     // 0..1023
  const int t = threadIdx.x;    // 0..511 (one column each)
  const int cnt = counts[c];
  const int end = offsets[c];   // segment END
  const int start = end - cnt;
  float v, cp;
  if (cnt > 0) {
    float s0 = 0.f, s1 = 0.f, s2 = 0.f, s3 = 0.f;
    float q0 = 0.f, q1 = 0.f, q2 = 0.f, q3 = 0.f;
    int i = start;
    for (; i + 4 <= end; i += 4) {
      const int r0 = order[i], r1 = order[i + 1], r2 = order[i + 2], r3 = order[i + 3];
      float x0 = cls[(size_t)r0 * HID + t];
      float x1 = cls[(size_t)r1 * HID + t];
      float x2 = cls[(size_t)r2 * HID + t];
      float x3 = cls[(size_t)r3 * HID + t];
      s0 += x0; q0 = fmaf(x0, x0, q0);
      s1 += x1; q1 = fmaf(x1, x1, q1);
      s2 += x2; q2 = fmaf(x2, x2, q2);
      s3 += x3; q3 = fmaf(x3, x3, q3);
    }
    for (; i < end; ++i) {
      float x = cls[(size_t)order[i] * HID + t];
      s0 += x; q0 = fmaf(x, x, q0);
    }
    v = ((s0 + s1) + (s2 + s3)) / (float)cnt;
    cp = ((q0 + q1) + (q2 + q3)) - (float)cnt * v * v;
  } else {
    v = (c < NCLS) ? cen_in[(size_t)c * HID + t] : 0.f;
    cp = 0.f;
  }
  cen[(size_t)c * HID + t] = v;

  float p = v * v;
  #pragma unroll
  for (int s = 32; s; s >>= 1) { p += __shfl_xor(p, s); cp += __shfl_xor(cp, s); }
  if ((t & 63) == 0) { red[t >> 6] = p; redc[t >> 6] = cp; }
  __syncthreads();
  if (t == 0) {
    float acc = 0.f, accc = 0.f;
    #pragma unroll
    for (int i = 0; i < 8; ++i) { acc += red[i]; accc += redc[i]; }
    sq[c] = acc;
    atomicAdd(accum + 1, (double)accc);
  }
}

// ---------------- separation: Gram + exp-sum (round-12 version) ----------------
__global__ void k_sep(const float* __restrict__ cen, const float* __restrict__ sq,
                      double* __restrict__ accum) {
  __shared__ float As[16][64];
  __shared__ float Bs[16][64];
  __shared__ float red[4];
  const int bi = blockIdx.x >> 4, bj = blockIdx.x & 15;
  const int tx = threadIdx.x & 15, ty = threadIdx.x >> 4;
  const int lrow = threadIdx.x & 63, lkq = threadIdx.x >> 6;
  float acc[4][4] = {};
  for (int k0 = 0; k0 < HID; k0 += 16) {
    __syncthreads();
    float4 a = *(const float4*)(cen + (size_t)(bi * 64 + lrow) * HID + k0 + lkq * 4);
    float4 b = *(const float4*)(cen + (size_t)(bj * 64 + lrow) * HID + k0 + lkq * 4);
    As[lkq*4+0][lrow] = a.x; As[lkq*4+1][lrow] = a.y; As[lkq*4+2][lrow] = a.z; As[lkq*4+3][lrow] = a.w;
    Bs[lkq*4+0][lrow] = b.x; Bs[lkq*4+1][lrow] = b.y; Bs[lkq*4+2][lrow] = b.z; Bs[lkq*4+3][lrow] = b.w;
    __syncthreads();
    #pragma unroll
    for (int k = 0; k < 16; ++k) {
      float4 av = *(const float4*)&As[k][ty * 4];
      float4 bv = *(const float4*)&Bs[k][tx * 4];
      float ar[4] = {av.x, av.y, av.z, av.w};
      float br[4] = {bv.x, bv.y, bv.z, bv.w};
      #pragma unroll
      for (int r = 0; r < 4; ++r)
        #pragma unroll
        for (int s = 0; s < 4; ++s)
          acc[r][s] = fmaf(ar[r], br[s], acc[r][s]);
    }
  }
  float part = 0.f;
  #pragma unroll
  for (int r = 0; r < 4; ++r) {
    const int i = bi * 64 + ty * 4 + r;
    #pragma unroll
    for (int s = 0; s < 4; ++s) {
      const int j = bj * 64 + tx * 4 + s;
      if (i < NCLS && j < NCLS) {
        float d2 = fmaxf(sq[i] + sq[j] - 2.f * acc[r][s], 0.f);
        float dist = sqrtf(d2);
        part += __expf((i == j ? 1.f : 0.f) - dist);
      }
    }
  }
  #pragma unroll
  for (int s = 32; s; s >>= 1) part += __shfl_xor(part, s);
  if ((threadIdx.x & 63) == 0) red[threadIdx.x >> 6] = part;
  __syncthreads();
  if (threadIdx.x == 0)
    atomicAdd(accum + 2, (double)(red[0] + red[1] + red[2] + red[3]));
}

// ---------------- fused stab: in-kernel fp8 staging + MFMA (B-prefetch) + epilogue ----------------
// (round-12 kernel, byte-identical — 166 us, VGPR 32, occ 84%)
__global__ __launch_bounds__(1024, 8)
void k_gemm(const float* __restrict__ cls, const float* __restrict__ noise,
            const float* __restrict__ logits, const int* __restrict__ labels,
            const float* __restrict__ bias, const u8* __restrict__ wb,
            double* __restrict__ accum) {
  __shared__ u8 Apan[32 * 512];      // 16 KB fp8 A-panel (swizzled)
  __shared__ u8 lntile[32 * 1024];   // 32 KB fp8 ln tile
  __shared__ float redf[32];
  const int lane = threadIdx.x & 63;
  const int w = threadIdx.x >> 6;    // 0..15
  const int row0 = blockIdx.x * 32;
  const int l15 = lane & 15, lkg = lane >> 4;

  // ---- phase 0: stage 32x512 fp8 A-panel (16 elems/thread, XOR-swizzled dest) ----
  {
    const int row_loc = threadIdx.x >> 5;            // 0..31
    const int k0 = (threadIdx.x & 31) * 16;          // 16 elems per thread
    const int sw = ((row_loc & 7) << 3) | (((row_loc >> 3) & 1) << 6);
    const float* cp = cls   + (size_t)(row0 + row_loc) * HID;
    const float* np = noise + (size_t)(row0 + row_loc) * HID;
    #pragma unroll
    for (int q = 0; q < 2; ++q) {
      const int g = k0 + q * 8;
      const int k = g ^ sw;
      float4 a0 = *(const float4*)(cp + k), a1 = *(const float4*)(cp + k + 4);
      float4 n0 = *(const float4*)(np + k), n1 = *(const float4*)(np + k + 4);
      uint2 p;
      p.x = pk4(fmaf(0.1f, n0.x, a0.x), fmaf(0.1f, n0.y, a0.y),
                fmaf(0.1f, n0.z, a0.z), fmaf(0.1f, n0.w, a0.w));
      p.y = pk4(fmaf(0.1f, n1.x, a1.x), fmaf(0.1f, n1.y, a1.y),
                fmaf(0.1f, n1.z, a1.z), fmaf(0.1f, n1.w, a1.w));
      *(uint2*)&Apan[row_loc * 512 + g] = p;
    }
  }
  __syncthreads();

  // ---- phase 2: 16 K-steps with one-deep register B-prefetch ----
  f32x4 acc[2][4] = {};
  const int swr = ((l15 & 7) << 3) | ((l15 >> 3) << 6);
  const u8* bb0 = wb + (w * 64 + l15) * 32 + lkg * 8;
  i64 bcur[4];
  #pragma unroll
  for (int ct = 0; ct < 4; ++ct) bcur[ct] = *(const i64*)(bb0 + ct * 512);
  for (int kc = 0; kc < 16; ++kc) {
    const int kn = (kc < 15) ? kc + 1 : 15;          // clamped prefetch index (uniform)
    const u8* bbn = bb0 + (size_t)kn * 32768;
    i64 bnxt[4];
    #pragma unroll
    for (int ct = 0; ct < 4; ++ct) bnxt[ct] = *(const i64*)(bbn + ct * 512);
    i64 af0 = *(const i64*)&Apan[(l15)      * 512 + ((kc * 32 + lkg * 8) ^ swr)];
    i64 af1 = *(const i64*)&Apan[(16 + l15) * 512 + ((kc * 32 + lkg * 8) ^ swr)];
    #pragma unroll
    for (int ct = 0; ct < 4; ++ct) {
      acc[0][ct] = __builtin_amdgcn_mfma_f32_16x16x32_fp8_fp8(af0, bcur[ct], acc[0][ct], 0, 0, 0);
      acc[1][ct] = __builtin_amdgcn_mfma_f32_16x16x32_fp8_fp8(af1, bcur[ct], acc[1][ct], 0, 0, 0);
    }
    #pragma unroll
    for (int ct = 0; ct < 4; ++ct) bcur[ct] = bnxt[ct];
  }

  // ---- phase 3a: ln = acc/16 + bias -> fp8 into lntile ----
  #pragma unroll
  for (int ct = 0; ct < 4; ++ct) {
    const int col = w * 64 + ct * 16 + l15;
    if (col < NCLS) {
      const float bc = bias[col];
      #pragma unroll
      for (int rt = 0; rt < 2; ++rt) {
        #pragma unroll
        for (int r = 0; r < 4; ++r) {
          const int rowloc = rt * 16 + lkg * 4 + r;
          lntile[rowloc * 1024 + (col ^ ((rowloc & 12) << 2))] =
              pk1(fmaf(acc[rt][ct][r], 0.0625f, bc));
        }
      }
    }
  }
  __syncthreads();

  // ---- phase 3b: single coalesced pass over logits: diff^2 + brier (no max-sub) ----
  float spart = 0.f, bpart = 0.f;
  #pragma unroll
  for (int j = 0; j < 2; ++j) {
    const int rowloc = w * 2 + j;
    const int row = row0 + rowloc;
    const int swz = (rowloc & 12) << 2;
    const u8* lnrow = lntile + rowloc * 1024;
    const float4* lr = (const float4*)(logits + (size_t)row * NCLS);
    const int lab2 = labels[row];
    const float el = __expf(logits[(size_t)row * NCLS + lab2]);
    float S = 0.f, S2 = 0.f;
    #pragma unroll
    for (int it = 0; it < 4; ++it) {
      const int f = it * 64 + lane;
      if (f < 250) {
        float4 lg = lr[f];
        u32 v = *(const u32*)(lnrow + ((f * 4) ^ swz));
        f32x2 lo = __builtin_amdgcn_cvt_pk_f32_fp8((int)v, false);
        f32x2 hi = __builtin_amdgcn_cvt_pk_f32_fp8((int)v, true);
        float d0 = lo[0] - lg.x, d1 = lo[1] - lg.y, d2 = hi[0] - lg.z, d3 = hi[1] - lg.w;
        spart += d0 * d0 + d1 * d1 + d2 * d2 + d3 * d3;
        float e0 = __expf(lg.x), e1 = __expf(lg.y), e2 = __expf(lg.z), e3 = __expf(lg.w);
        S += e0 + e1 + e2 + e3;
        S2 += e0 * e0 + e1 * e1 + e2 * e2 + e3 * e3;
      }
    }
    #pragma unroll
    for (int s = 32; s; s >>= 1) { S += __shfl_xor(S, s); S2 += __shfl_xor(S2, s); }
    bpart += S2 / (S * S) - 2.f * el / S + 1.f;
  }
  #pragma unroll
  for (int s = 32; s; s >>= 1) { spart += __shfl_xor(spart, s); bpart += __shfl_xor(bpart, s); }

  if (lane == 0) { redf[w] = spart; redf[16 + w] = bpart; }
  __syncthreads();
  if (threadIdx.x == 0) {
    float st = 0.f, br = 0.f;
    #pragma unroll
    for (int i = 0; i < 16; ++i) { st += redf[i]; br += redf[16 + i]; }
    atomicAdd(accum + 0, (double)st);
    atomicAdd(accum + 3, (double)br);
  }
}

// ---------------- combine ----------------
__global__ void k_final(const double* __restrict__ accum, float* __restrict__ out) {
  if (threadIdx.x == 0) {
    double stab   = accum[0] / ((double)BATCH * (double)NCLS);
    double center = accum[1] / ((double)BATCH * (double)HID);
    double sep    = accum[2] - (double)NCLS;
    double brier  = accum[3] / (double)BATCH;
    double total  = 1.0 * stab + 0.1 * center + 0.01 * sep + 1.0 * brier;
    out[0] = (float)total;
    out[1] = (float)stab;
    out[2] = (float)center;
    out[3] = (float)sep;
    out[4] = (float)brier;
  }
}

extern "C" void kernel_launch(void* const* d_in, const int* in_sizes, int n_in,
                              void* d_out, int out_size, void* d_ws, size_t ws_size,
                              hipStream_t stream) {
  const float* cls    = (const float*)d_in[0];
  const float* logits = (const float*)d_in[1];
  const int*   labels = (const int*)d_in[2];
  const float* W      = (const float*)d_in[3];
  const float* bias   = (const float*)d_in[4];
  const float* noise  = (const float*)d_in[5];
  const float* cen_in = (const float*)d_in[6];
  float* out = (float*)d_out;
  char* ws = (char*)d_ws;
  if (ws_size < (size_t)WS_END) return;  // fail visibly (out stays poisoned)

  int*    counts  = (int*)(ws + 0);
  int*    cursor  = (int*)(ws + 4096);
  double* accum   = (double*)(ws + 8192);
  float*  sq      = (float*)(ws + 12288);
  int*    offsets = (int*)(ws + 16384);
  int*    order   = (int*)(ws + 20480);
  float*  cen     = (float*)(ws + 282624);
  u8*     wb8     = (u8*)(ws + 2383872);

  hipLaunchKernelGGL(k_zero,    dim3(1),    dim3(1024), 0, stream, counts, cursor, accum);
  hipLaunchKernelGGL(k_hist,    dim3(256),  dim3(256),  0, stream, labels, counts);
  hipLaunchKernelGGL(k_wconv,   dim3(512),  dim3(256),  0, stream, W, (u32*)wb8);
  hipLaunchKernelGGL(k_scatter, dim3(64),   dim3(1024), 0, stream, labels, counts, cursor, offsets, order);
  hipLaunchKernelGGL(k_segsum,  dim3(1024), dim3(512),  0, stream, cls, order, offsets, counts, cen_in, cen, sq, accum);
  hipLaunchKernelGGL(k_sep,     dim3(256),  dim3(256),  0, stream, cen, sq, accum);
  hipLaunchKernelGGL(k_gemm,    dim3(2048), dim3(1024), 0, stream, cls, noise, logits, labels, bias, wb8, accum);
  hipLaunchKernelGGL(k_final,   dim3(1),    dim3(64),   0, stream, accum, out);
}